// Round 4
// baseline (366.113 us; speedup 1.0000x reference)
//
#include <hip/hip_runtime.h>

// Transformer layer, MI355X/gfx950.
// B=2, N=2048, C=512, H=8, D=64. Softmax over HEAD axis (faithful to ref).
// Attention v4: barrier-free streaming. One block = one 16-row n-strip,
// 8 waves m-split 256 each, all 8 heads in-lane (no exchange), K/V/Q
// gathered directly from L2 (no LDS staging, no mid-loop barriers),
// intra-block LDS ds_add_f32 combine -> bf16 store (NO global atomics).

typedef unsigned short u16;
typedef unsigned int u32;
typedef __attribute__((ext_vector_type(4))) float f32x4;
typedef __attribute__((ext_vector_type(4))) u32 u32x4;
typedef __attribute__((ext_vector_type(8))) short sv8;
typedef __attribute__((ext_vector_type(8))) __bf16 bfv8;
typedef __attribute__((ext_vector_type(8))) u16 usv8;
typedef __attribute__((ext_vector_type(4))) u16 usv4;

#define DEV static __device__ __forceinline__

DEV u16 f2bf(float f) {  // RNE fp32 -> bf16
  u32 x = __builtin_bit_cast(u32, f);
  return (u16)((x + 0x7fffu + ((x >> 16) & 1u)) >> 16);
}

DEV f32x4 mfma16(sv8 a, sv8 b, f32x4 c) {
  return __builtin_amdgcn_mfma_f32_16x16x32_bf16(
      __builtin_bit_cast(bfv8, a), __builtin_bit_cast(bfv8, b), c, 0, 0, 0);
}

DEV void gload_lds16(const void* g, void* l) {
  __builtin_amdgcn_global_load_lds(
      (const __attribute__((address_space(1))) u32*)g,
      (__attribute__((address_space(3))) u32*)l, 16, 0, 0);
}

DEV u32 pkbf(float a, float b) {
  u32 r;
  asm("v_cvt_pk_bf16_f32 %0, %1, %2" : "=v"(r) : "v"(a), "v"(b));
  return r;
}

// ---------------- weight cast: 4 fp32 weight mats -> bf16 ----------------
__global__ __launch_bounds__(256) void cast_w(
    const float* __restrict__ s0, const float* __restrict__ s1,
    const float* __restrict__ s2, const float* __restrict__ s3,
    u16* __restrict__ d0, u16* __restrict__ d1,
    u16* __restrict__ d2, u16* __restrict__ d3)
{
  int i = blockIdx.x * 256 + threadIdx.x;  // vec4 index, 786432 total
  const float* s; u16* d; int off;
  if (i < 196608)      { s = s0; d = d0; off = i; }
  else if (i < 262144) { s = s1; d = d1; off = i - 196608; }
  else if (i < 524288) { s = s2; d = d2; off = i - 262144; }
  else                 { s = s3; d = d3; off = i - 524288; }
  float4 v = ((const float4*)s)[off];
  usv4 r; r.x = f2bf(v.x); r.y = f2bf(v.y); r.z = f2bf(v.z); r.w = f2bf(v.w);
  *(usv4*)(d + (size_t)off * 4) = r;
}

// ---------------- layernorm (C=512) fp32 in -> bf16 out ----------------
__global__ __launch_bounds__(256) void ln_kernel(
    const float* __restrict__ x, const float* __restrict__ g,
    const float* __restrict__ bb, u16* __restrict__ out)
{
  const int row = (blockIdx.x << 2) + (threadIdx.x >> 6);
  const int lane = threadIdx.x & 63;
  const float4* xr = (const float4*)(x + ((size_t)row << 9));
  float4 a = xr[lane * 2], c = xr[lane * 2 + 1];
  float s  = a.x + a.y + a.z + a.w + c.x + c.y + c.z + c.w;
  float ss = a.x*a.x + a.y*a.y + a.z*a.z + a.w*a.w
           + c.x*c.x + c.y*c.y + c.z*c.z + c.w*c.w;
  #pragma unroll
  for (int off = 32; off; off >>= 1) { s += __shfl_xor(s, off); ss += __shfl_xor(ss, off); }
  const float mu = s * (1.0f / 512.0f);
  const float rstd = rsqrtf(ss * (1.0f / 512.0f) - mu * mu + 1e-6f);
  const float4* g4 = (const float4*)g;
  const float4* b4 = (const float4*)bb;
  float4 g0 = g4[lane * 2], g1 = g4[lane * 2 + 1];
  float4 b0 = b4[lane * 2], b1 = b4[lane * 2 + 1];
  usv8 rr;
  rr[0] = f2bf((a.x - mu) * rstd * g0.x + b0.x);
  rr[1] = f2bf((a.y - mu) * rstd * g0.y + b0.y);
  rr[2] = f2bf((a.z - mu) * rstd * g0.z + b0.z);
  rr[3] = f2bf((a.w - mu) * rstd * g0.w + b0.w);
  rr[4] = f2bf((c.x - mu) * rstd * g1.x + b1.x);
  rr[5] = f2bf((c.y - mu) * rstd * g1.y + b1.y);
  rr[6] = f2bf((c.z - mu) * rstd * g1.z + b1.z);
  rr[7] = f2bf((c.w - mu) * rstd * g1.w + b1.w);
  *(usv8*)(out + ((size_t)row << 9) + (lane << 3)) = rr;
}

// ---------------- GEMM: out[m][o] = sum_c A[m][c] * W[o][c] (+epilogue) ----
// EPI 0: bf16 store. EPI 1: f32 store = acc + bias + res. EPI 2: bf16 gelu(acc+bias).
template<int EPI>
__global__ __launch_bounds__(256, 2) void gemm_kernel(
    const u16* __restrict__ A, const u16* __restrict__ W,
    int K, int Nn, const float* __restrict__ bias,
    const float* __restrict__ res, void* __restrict__ outp)
{
  __shared__ u16 sA[128 * 64];
  __shared__ u16 sB[128 * 64];
  const int m0 = blockIdx.x << 7, n0 = blockIdx.y << 7;
  const int lane = threadIdx.x & 63, wave = threadIdx.x >> 6;
  const int wm = wave >> 1, wn = wave & 1;
  const int srow = lane >> 3, scol = (lane & 7) << 3;
  const int l15 = lane & 15, l4 = lane >> 4;
  f32x4 acc[4][4] = {};
  for (int kt = 0; kt < K; kt += 64) {
    #pragma unroll
    for (int i = 0; i < 4; ++i) {
      const int c = (wave << 2) + i;
      gload_lds16(A + (size_t)(m0 + (c << 3) + srow) * K + kt + scol, sA + (c << 9));
      gload_lds16(W + (size_t)(n0 + (c << 3) + srow) * K + kt + scol, sB + (c << 9));
    }
    __syncthreads();
    #pragma unroll
    for (int kk = 0; kk < 2; ++kk) {
      sv8 af[4], bfr[4];
      #pragma unroll
      for (int mi = 0; mi < 4; ++mi)
        af[mi] = *(const sv8*)(sA + (wm * 64 + mi * 16 + l15) * 64 + kk * 32 + (l4 << 3));
      #pragma unroll
      for (int ni = 0; ni < 4; ++ni)
        bfr[ni] = *(const sv8*)(sB + (wn * 64 + ni * 16 + l15) * 64 + kk * 32 + (l4 << 3));
      #pragma unroll
      for (int mi = 0; mi < 4; ++mi)
        #pragma unroll
        for (int ni = 0; ni < 4; ++ni)
          acc[mi][ni] = mfma16(af[mi], bfr[ni], acc[mi][ni]);
    }
    __syncthreads();
  }
  float bias_v[4];
  if (EPI != 0) {
    #pragma unroll
    for (int ni = 0; ni < 4; ++ni)
      bias_v[ni] = bias[n0 + wn * 64 + ni * 16 + l15];
  }
  #pragma unroll
  for (int mi = 0; mi < 4; ++mi) {
    #pragma unroll
    for (int ni = 0; ni < 4; ++ni) {
      const int gcol = n0 + wn * 64 + ni * 16 + l15;
      #pragma unroll
      for (int r = 0; r < 4; ++r) {
        const int grow = m0 + wm * 64 + mi * 16 + (l4 << 2) + r;
        float v = acc[mi][ni][r];
        if (EPI == 0) {
          ((u16*)outp)[(size_t)grow * Nn + gcol] = f2bf(v);
        } else if (EPI == 1) {
          ((float*)outp)[(size_t)grow * Nn + gcol] =
              v + bias_v[ni] + res[(size_t)grow * Nn + gcol];
        } else {
          float t = v + bias_v[ni];
          float gl = 0.5f * t * (1.0f + erff(t * 0.70710678118654752f));
          ((u16*)outp)[(size_t)grow * Nn + gcol] = f2bf(gl);
        }
      }
    }
  }
}

// ---------------- V transpose: qkv V-part -> vt[b][h][d][n] ----------------
__global__ __launch_bounds__(256) void transpose_v(
    const u16* __restrict__ qkvb, u16* __restrict__ vt)
{
  __shared__ u16 tile[64][72];
  const int bh = blockIdx.y, n0 = blockIdx.x << 6;
  const int b = bh >> 3, h = bh & 7;
  const int t = threadIdx.x;
  const int row = t >> 2, d0 = (t & 3) << 4;
  const u16* src = qkvb + (size_t)(b * 2048 + n0 + row) * 1536 + 1024 + h * 64 + d0;
  *(uint4*)&tile[row][d0]     = *(const uint4*)src;
  *(uint4*)&tile[row][d0 + 8] = *(const uint4*)(src + 8);
  __syncthreads();
  const int dr = t >> 2, nn0 = (t & 3) << 4;
  u16* dst = vt + (size_t)(bh * 64 + dr) * 2048 + n0 + nn0;
  usv8 v0, v1;
  #pragma unroll
  for (int j = 0; j < 8; ++j) v0[j] = tile[nn0 + j][dr];
  #pragma unroll
  for (int j = 0; j < 8; ++j) v1[j] = tile[nn0 + 8 + j][dr];
  *(usv8*)dst = v0;
  *(usv8*)(dst + 8) = v1;
}

// ---------------- fused attention v4 (softmax over heads) ----------------
// 256 blocks x 512 thr. Block = (b, 16-row n-strip); wave w = m-slice
// [w*256, w*256+256), 8 tiles of 32 m, all 8 heads in-lane. No LDS staging,
// no mid-loop barriers; K/V/Q gathered from L2. End: ds_add_f32 combine.
__global__ __launch_bounds__(512, 2) void attn_kernel(
    const u16* __restrict__ qkvb, const u16* __restrict__ vt,
    u16* __restrict__ attnb)
{
  __shared__ float slab[16 * 512];
  const int tid = threadIdx.x;
  const int lane = tid & 63, w = tid >> 6;
  const int l15 = lane & 15, g = lane >> 4;
  const int bid = blockIdx.x;
  const int xcd = bid & 7;                       // keep one b per XCD quartet
  const int b = xcd >> 2;
  const int strip = ((xcd & 3) << 5) | (bid >> 3);
  const int row0 = strip << 4;
  const float KSC = 0.125f * 1.4426950408889634f;  // scale * log2(e)

  #pragma unroll
  for (int i = 0; i < 4; ++i)
    *(f32x4*)&slab[tid * 16 + i * 4] = f32x4{0.f, 0.f, 0.f, 0.f};
  __syncthreads();

  const int lvK = l15 * 1536 + g * 8;   // lane-varying offsets (u16 units)
  const int lvV = l15 * 2048 + g * 8;
  const u16* qb  = qkvb + (size_t)(b * 2048 + row0) * 1536 + lvK;
  const u16* vbb = vt + (size_t)b * 512 * 2048 + lvV;

  f32x4 acc[8][4] = {};

  #pragma unroll 2
  for (int t = 0; t < 8; ++t) {
    const int mb = (w << 8) + (t << 5);
    const u16* kb0 = qkvb + (size_t)(b * 2048 + mb) * 1536 + 512 + lvK;
    const u16* kb1 = kb0 + 16 * 1536;
    const u16* vb = vbb + mb;
    float sums[8] = {0.f,0.f,0.f,0.f,0.f,0.f,0.f,0.f};
    u32 pe[8][4];
    #pragma unroll
    for (int h = 0; h < 8; ++h) {
      sv8 q0 = *(const sv8*)(qb + h * 64);
      sv8 q1 = *(const sv8*)(qb + h * 64 + 32);
      sv8 k00 = *(const sv8*)(kb0 + h * 64);
      sv8 k01 = *(const sv8*)(kb0 + h * 64 + 32);
      sv8 k10 = *(const sv8*)(kb1 + h * 64);
      sv8 k11 = *(const sv8*)(kb1 + h * 64 + 32);
      f32x4 s0 = {0.f,0.f,0.f,0.f}, s1 = {0.f,0.f,0.f,0.f};
      s0 = mfma16(k00, q0, s0); s0 = mfma16(k01, q1, s0);
      s1 = mfma16(k10, q0, s1); s1 = mfma16(k11, q1, s1);
      float e[8];
      #pragma unroll
      for (int r = 0; r < 4; ++r) { e[r]     = exp2f(s0[r] * KSC); sums[r]     += e[r]; }
      #pragma unroll
      for (int r = 0; r < 4; ++r) { e[4 + r] = exp2f(s1[r] * KSC); sums[4 + r] += e[4 + r]; }
      pe[h][0] = pkbf(e[0], e[1]); pe[h][1] = pkbf(e[2], e[3]);
      pe[h][2] = pkbf(e[4], e[5]); pe[h][3] = pkbf(e[6], e[7]);
    }
    float inv[8];
    #pragma unroll
    for (int j = 0; j < 8; ++j) inv[j] = __builtin_amdgcn_rcpf(sums[j]);
    #pragma unroll
    for (int h = 0; h < 8; ++h) {
      float p[8];
      #pragma unroll
      for (int jj = 0; jj < 4; ++jj) {
        const u32 v = pe[h][jj];
        p[jj * 2]     = __builtin_bit_cast(float, v << 16) * inv[jj * 2];
        p[jj * 2 + 1] = __builtin_bit_cast(float, v & 0xffff0000u) * inv[jj * 2 + 1];
      }
      u32 pa = pkbf(p[0], p[1]), pc = pkbf(p[2], p[3]);
      u32 pb_ = pkbf(p[4], p[5]), pd = pkbf(p[6], p[7]);
      asm("v_permlane32_swap_b32 %0, %1" : "+v"(pa), "+v"(pb_));
      asm("v_permlane16_swap_b32 %0, %1" : "+v"(pa), "+v"(pb_));
      asm("v_permlane32_swap_b32 %0, %1" : "+v"(pc), "+v"(pd));
      asm("v_permlane16_swap_b32 %0, %1" : "+v"(pc), "+v"(pd));
      u32x4 pw; pw.x = pa; pw.y = pc; pw.z = pb_; pw.w = pd;
      sv8 pf = __builtin_bit_cast(sv8, pw);
      #pragma unroll
      for (int dsub = 0; dsub < 4; ++dsub) {
        sv8 vf = *(const sv8*)(vb + (size_t)((h << 6) + (dsub << 4)) * 2048);
        acc[h][dsub] = mfma16(pf, vf, acc[h][dsub]);
      }
    }
  }
  // ---- intra-block combine (LDS f32 atomics), then bf16 store ----
  #pragma unroll
  for (int h = 0; h < 8; ++h)
    #pragma unroll
    for (int dsub = 0; dsub < 4; ++dsub)
      #pragma unroll
      for (int r = 0; r < 4; ++r)
        atomicAdd(&slab[(((g << 2) + r) << 9) + (h << 6) + (dsub << 4) + l15],
                  acc[h][dsub][r]);
  __syncthreads();
  {
    const int row = tid >> 5, c0 = (tid & 31) << 4;
    const float* src = &slab[(row << 9) + c0];
    u16* dst = attnb + (size_t)(b * 2048 + row0 + row) * 512 + c0;
    #pragma unroll
    for (int q = 0; q < 2; ++q) {
      usv8 rr;
      #pragma unroll
      for (int j = 0; j < 8; ++j) rr[j] = f2bf(src[q * 8 + j]);
      *(usv8*)(dst + q * 8) = rr;
    }
  }
}

extern "C" void kernel_launch(void* const* d_in, const int* in_sizes, int n_in,
                              void* d_out, int out_size, void* d_ws, size_t ws_size,
                              hipStream_t stream) {
  const float* x      = (const float*)d_in[0];
  const float* ln_g   = (const float*)d_in[1];
  const float* ln_b   = (const float*)d_in[2];
  const float* qkv_w  = (const float*)d_in[3];
  const float* proj_w = (const float*)d_in[4];
  const float* proj_b = (const float*)d_in[5];
  const float* fc1_w  = (const float*)d_in[6];
  const float* fc1_b  = (const float*)d_in[7];
  const float* fc2_w  = (const float*)d_in[8];
  const float* fc2_b  = (const float*)d_in[9];
  char* ws = (char*)d_ws;
  u16*   w_qkv  = (u16*)(ws + 0);         // 1536x512 bf16
  u16*   w_proj = (u16*)(ws + 1572864);   // 512x512
  u16*   w_fc1  = (u16*)(ws + 2097152);   // 2048x512
  u16*   w_fc2  = (u16*)(ws + 4194304);   // 512x2048
  u16*   xn     = (u16*)(ws + 6291456);   // 4096x512 bf16 (LN out, reused)
  u16*   qkvb   = (u16*)(ws + 10485760);  // 4096x1536 bf16
  u16*   vtb    = (u16*)(ws + 23068672);  // [2][8][64][2048] bf16
  u16*   attnb  = (u16*)(ws + 35651584);  // 4096x512 bf16
  float* x1     = (float*)(ws + 39845888);// 4096x512 f32
  u16*   hbuf   = (u16*)(ws + 48234496);  // 4096x2048 bf16   (end: 62MB)

  cast_w<<<3072, 256, 0, stream>>>(qkv_w, proj_w, fc1_w, fc2_w,
                                   w_qkv, w_proj, w_fc1, w_fc2);
  ln_kernel<<<1024, 256, 0, stream>>>(x, ln_g, ln_b, xn);
  gemm_kernel<0><<<dim3(32, 12), 256, 0, stream>>>(xn, w_qkv, 512, 1536,
                                                   nullptr, nullptr, qkvb);
  transpose_v<<<dim3(32, 16), 256, 0, stream>>>(qkvb, vtb);
  attn_kernel<<<256, 512, 0, stream>>>(qkvb, vtb, attnb);
  gemm_kernel<1><<<dim3(32, 4), 256, 0, stream>>>(attnb, w_proj, 512, 512,
                                                  proj_b, x, x1);
  ln_kernel<<<1024, 256, 0, stream>>>(x1, ln_g, ln_b, xn);
  gemm_kernel<2><<<dim3(32, 16), 256, 0, stream>>>(xn, w_fc1, 512, 2048,
                                                   fc1_b, nullptr, hbuf);
  gemm_kernel<1><<<dim3(32, 4), 256, 0, stream>>>(hbuf, w_fc2, 2048, 512,
                                                  fc2_b, x1, d_out);
}

// Round 5
// 192.532 us; speedup vs baseline: 1.9016x; 1.9016x over previous
//
#include <hip/hip_runtime.h>

// Transformer layer, MI355X/gfx950.
// B=2, N=2048, C=512, H=8, D=64. Softmax over HEAD axis (faithful to ref).
// Attention v5: 4 head-pair waves share LDS K/V tiles (no redundant QK),
// bf16 denominator exchange folded into the 2-barrier pipelined tile loop,
// m-split 2 across blocks with plain bf16 partial stores (NO global atomics),
// small acc (64 f32) -> no spills. Combine kernel sums the two partials.

typedef unsigned short u16;
typedef unsigned int u32;
typedef __attribute__((ext_vector_type(4))) float f32x4;
typedef __attribute__((ext_vector_type(4))) u32 u32x4;
typedef __attribute__((ext_vector_type(8))) short sv8;
typedef __attribute__((ext_vector_type(8))) __bf16 bfv8;
typedef __attribute__((ext_vector_type(8))) u16 usv8;
typedef __attribute__((ext_vector_type(4))) u16 usv4;

#define DEV static __device__ __forceinline__

DEV u16 f2bf(float f) {  // RNE fp32 -> bf16
  u32 x = __builtin_bit_cast(u32, f);
  return (u16)((x + 0x7fffu + ((x >> 16) & 1u)) >> 16);
}

DEV float bf2f(u16 v) { return __builtin_bit_cast(float, (u32)v << 16); }

DEV f32x4 mfma16(sv8 a, sv8 b, f32x4 c) {
  return __builtin_amdgcn_mfma_f32_16x16x32_bf16(
      __builtin_bit_cast(bfv8, a), __builtin_bit_cast(bfv8, b), c, 0, 0, 0);
}

DEV void gload_lds16(const void* g, void* l) {
  __builtin_amdgcn_global_load_lds(
      (const __attribute__((address_space(1))) u32*)g,
      (__attribute__((address_space(3))) u32*)l, 16, 0, 0);
}

DEV u32 pkbf(float a, float b) {
  u32 r;
  asm("v_cvt_pk_bf16_f32 %0, %1, %2" : "=v"(r) : "v"(a), "v"(b));
  return r;
}

// ---------------- weight cast: 4 fp32 weight mats -> bf16 ----------------
__global__ __launch_bounds__(256) void cast_w(
    const float* __restrict__ s0, const float* __restrict__ s1,
    const float* __restrict__ s2, const float* __restrict__ s3,
    u16* __restrict__ d0, u16* __restrict__ d1,
    u16* __restrict__ d2, u16* __restrict__ d3)
{
  int i = blockIdx.x * 256 + threadIdx.x;  // vec4 index, 786432 total
  const float* s; u16* d; int off;
  if (i < 196608)      { s = s0; d = d0; off = i; }
  else if (i < 262144) { s = s1; d = d1; off = i - 196608; }
  else if (i < 524288) { s = s2; d = d2; off = i - 262144; }
  else                 { s = s3; d = d3; off = i - 524288; }
  float4 v = ((const float4*)s)[off];
  usv4 r; r.x = f2bf(v.x); r.y = f2bf(v.y); r.z = f2bf(v.z); r.w = f2bf(v.w);
  *(usv4*)(d + (size_t)off * 4) = r;
}

// ---------------- layernorm (C=512) fp32 in -> bf16 out ----------------
__global__ __launch_bounds__(256) void ln_kernel(
    const float* __restrict__ x, const float* __restrict__ g,
    const float* __restrict__ bb, u16* __restrict__ out)
{
  const int row = (blockIdx.x << 2) + (threadIdx.x >> 6);
  const int lane = threadIdx.x & 63;
  const float4* xr = (const float4*)(x + ((size_t)row << 9));
  float4 a = xr[lane * 2], c = xr[lane * 2 + 1];
  float s  = a.x + a.y + a.z + a.w + c.x + c.y + c.z + c.w;
  float ss = a.x*a.x + a.y*a.y + a.z*a.z + a.w*a.w
           + c.x*c.x + c.y*c.y + c.z*c.z + c.w*c.w;
  #pragma unroll
  for (int off = 32; off; off >>= 1) { s += __shfl_xor(s, off); ss += __shfl_xor(ss, off); }
  const float mu = s * (1.0f / 512.0f);
  const float rstd = rsqrtf(ss * (1.0f / 512.0f) - mu * mu + 1e-6f);
  const float4* g4 = (const float4*)g;
  const float4* b4 = (const float4*)bb;
  float4 g0 = g4[lane * 2], g1 = g4[lane * 2 + 1];
  float4 b0 = b4[lane * 2], b1 = b4[lane * 2 + 1];
  usv8 rr;
  rr[0] = f2bf((a.x - mu) * rstd * g0.x + b0.x);
  rr[1] = f2bf((a.y - mu) * rstd * g0.y + b0.y);
  rr[2] = f2bf((a.z - mu) * rstd * g0.z + b0.z);
  rr[3] = f2bf((a.w - mu) * rstd * g0.w + b0.w);
  rr[4] = f2bf((c.x - mu) * rstd * g1.x + b1.x);
  rr[5] = f2bf((c.y - mu) * rstd * g1.y + b1.y);
  rr[6] = f2bf((c.z - mu) * rstd * g1.z + b1.z);
  rr[7] = f2bf((c.w - mu) * rstd * g1.w + b1.w);
  *(usv8*)(out + ((size_t)row << 9) + (lane << 3)) = rr;
}

// ---------------- GEMM: out[m][o] = sum_c A[m][c] * W[o][c] (+epilogue) ----
// EPI 0: bf16 store. EPI 1: f32 store = acc + bias + res. EPI 2: bf16 gelu(acc+bias).
template<int EPI>
__global__ __launch_bounds__(256, 2) void gemm_kernel(
    const u16* __restrict__ A, const u16* __restrict__ W,
    int K, int Nn, const float* __restrict__ bias,
    const float* __restrict__ res, void* __restrict__ outp)
{
  __shared__ u16 sA[128 * 64];
  __shared__ u16 sB[128 * 64];
  const int m0 = blockIdx.x << 7, n0 = blockIdx.y << 7;
  const int lane = threadIdx.x & 63, wave = threadIdx.x >> 6;
  const int wm = wave >> 1, wn = wave & 1;
  const int srow = lane >> 3, scol = (lane & 7) << 3;
  const int l15 = lane & 15, l4 = lane >> 4;
  f32x4 acc[4][4] = {};
  for (int kt = 0; kt < K; kt += 64) {
    #pragma unroll
    for (int i = 0; i < 4; ++i) {
      const int c = (wave << 2) + i;
      gload_lds16(A + (size_t)(m0 + (c << 3) + srow) * K + kt + scol, sA + (c << 9));
      gload_lds16(W + (size_t)(n0 + (c << 3) + srow) * K + kt + scol, sB + (c << 9));
    }
    __syncthreads();
    #pragma unroll
    for (int kk = 0; kk < 2; ++kk) {
      sv8 af[4], bfr[4];
      #pragma unroll
      for (int mi = 0; mi < 4; ++mi)
        af[mi] = *(const sv8*)(sA + (wm * 64 + mi * 16 + l15) * 64 + kk * 32 + (l4 << 3));
      #pragma unroll
      for (int ni = 0; ni < 4; ++ni)
        bfr[ni] = *(const sv8*)(sB + (wn * 64 + ni * 16 + l15) * 64 + kk * 32 + (l4 << 3));
      #pragma unroll
      for (int mi = 0; mi < 4; ++mi)
        #pragma unroll
        for (int ni = 0; ni < 4; ++ni)
          acc[mi][ni] = mfma16(af[mi], bfr[ni], acc[mi][ni]);
    }
    __syncthreads();
  }
  float bias_v[4];
  if (EPI != 0) {
    #pragma unroll
    for (int ni = 0; ni < 4; ++ni)
      bias_v[ni] = bias[n0 + wn * 64 + ni * 16 + l15];
  }
  #pragma unroll
  for (int mi = 0; mi < 4; ++mi) {
    #pragma unroll
    for (int ni = 0; ni < 4; ++ni) {
      const int gcol = n0 + wn * 64 + ni * 16 + l15;
      #pragma unroll
      for (int r = 0; r < 4; ++r) {
        const int grow = m0 + wm * 64 + mi * 16 + (l4 << 2) + r;
        float v = acc[mi][ni][r];
        if (EPI == 0) {
          ((u16*)outp)[(size_t)grow * Nn + gcol] = f2bf(v);
        } else if (EPI == 1) {
          ((float*)outp)[(size_t)grow * Nn + gcol] =
              v + bias_v[ni] + res[(size_t)grow * Nn + gcol];
        } else {
          float t = v + bias_v[ni];
          float gl = 0.5f * t * (1.0f + erff(t * 0.70710678118654752f));
          ((u16*)outp)[(size_t)grow * Nn + gcol] = f2bf(gl);
        }
      }
    }
  }
}

// ---------------- V transpose: qkv V-part -> vt[b][h][d][n] ----------------
__global__ __launch_bounds__(256) void transpose_v(
    const u16* __restrict__ qkvb, u16* __restrict__ vt)
{
  __shared__ u16 tile[64][72];
  const int bh = blockIdx.y, n0 = blockIdx.x << 6;
  const int b = bh >> 3, h = bh & 7;
  const int t = threadIdx.x;
  const int row = t >> 2, d0 = (t & 3) << 4;
  const u16* src = qkvb + (size_t)(b * 2048 + n0 + row) * 1536 + 1024 + h * 64 + d0;
  *(uint4*)&tile[row][d0]     = *(const uint4*)src;
  *(uint4*)&tile[row][d0 + 8] = *(const uint4*)(src + 8);
  __syncthreads();
  const int dr = t >> 2, nn0 = (t & 3) << 4;
  u16* dst = vt + (size_t)(bh * 64 + dr) * 2048 + n0 + nn0;
  usv8 v0, v1;
  #pragma unroll
  for (int j = 0; j < 8; ++j) v0[j] = tile[nn0 + j][dr];
  #pragma unroll
  for (int j = 0; j < 8; ++j) v1[j] = tile[nn0 + 8 + j][dr];
  *(usv8*)dst = v0;
  *(usv8*)(dst + 8) = v1;
}

// ---------------- fused attention v5 (softmax over heads) ----------------
// 256 blocks x 256 thr (4 waves). Block = 32 n-rows x 1024-m half; wave w
// owns heads {2w,2w+1} for all 32 rows. K/V tiles (32 m) shared via LDS,
// denominators exchanged as bf16 partials folded into the 2 barriers/tile.
__global__ __launch_bounds__(256, 2) void attn_kernel(
    const u16* __restrict__ qkvb, const u16* __restrict__ vt,
    u16* __restrict__ p0, u16* __restrict__ p1)
{
  __shared__ u16 sK[8 * 32 * 64];   // 32KB [h][m32][slot8], slot^=(m&7)
  __shared__ u16 sV[512 * 32];      // 32KB [h*64+d][slot4], slot^=((row>>1)&3)
  __shared__ u32 sSum[4 * 64 * 8];  // 8KB  per-wave bf16-packed partial sums
  const int tid = threadIdx.x;
  const int lane = tid & 63, w = tid >> 6;
  const int l15 = lane & 15, g = lane >> 4;

  const int swz = ((blockIdx.x & 7) << 5) + (blockIdx.x >> 3);  // XCD swizzle
  const int msplit = swz >> 7;
  const int strip = swz & 127;
  const int row0 = strip << 5;          // global row 0..4095
  const int b = row0 >> 11;
  const int m0 = msplit << 10;          // m-offset within batch
  u16* pbuf = msplit ? p1 : p0;
  const float KSC = 0.125f * 1.4426950408889634f;  // scale * log2(e)

  // ---- Q hoist: Q[hp][ns][kh], rows row0+ns*16+l15, head 2w+hp ----
  sv8 Q[2][2][2];
  #pragma unroll
  for (int hp = 0; hp < 2; ++hp)
    #pragma unroll
    for (int ns = 0; ns < 2; ++ns) {
      const u16* qp = qkvb + (size_t)(row0 + ns * 16 + l15) * 1536
                    + (w * 2 + hp) * 64 + g * 8;
      Q[hp][ns][0] = *(const sv8*)qp;
      Q[hp][ns][1] = *(const sv8*)(qp + 32);
    }

  // staging bases (pre-swizzled global sources, linear LDS dst)
  const u16* pK = qkvb + (size_t)(b * 2048 + m0 + (lane >> 3)) * 1536 + 512
                + ((lane & 7) ^ (lane >> 3)) * 8 + w * 128;
  const u16* pV = vt + (size_t)(b * 512 + w * 128 + (lane >> 2)) * 2048 + m0
                + ((lane & 3) ^ ((lane >> 3) & 3)) * 8;

  u32 pe[2][8];           // bf16-packed e-values, 2 heads
  sv8 pf[2][2];           // P^T A-frags [hp][ns]
  f32x4 acc[2][4][2] = {};
  u32* mySum = sSum + ((w << 6) + lane) * 8;

  auto stageK = [&](int t) {
    const u16* base = pK + (size_t)t * (32 * 1536);
    #pragma unroll
    for (int i = 0; i < 8; ++i)
      gload_lds16(base + (i >> 2) * 64 + (i & 3) * 12288,
                  sK + ((w << 3) + i) * 512);
  };
  auto stageV = [&](int t) {
    const u16* base = pV + t * 32;
    #pragma unroll
    for (int i = 0; i < 8; ++i)
      gload_lds16(base + (size_t)i * 32768, sV + ((w << 3) + i) * 512);
  };
  // QK^T for own 2 heads -> exp -> pe (packed) + partial sums -> LDS
  auto qk_step = [&]() {
    float tt[16];
    #pragma unroll
    for (int hp = 0; hp < 2; ++hp) {
      #pragma unroll
      for (int ms = 0; ms < 2; ++ms) {
        const int row = ((w * 2 + hp) * 32 + ms * 16 + l15) * 64;
        const int x7 = l15 & 7;
        sv8 k0 = *(const sv8*)(sK + row + ((g) ^ x7) * 8);
        sv8 k1 = *(const sv8*)(sK + row + ((4 + g) ^ x7) * 8);
        #pragma unroll
        for (int ns = 0; ns < 2; ++ns) {
          f32x4 s = {0.f, 0.f, 0.f, 0.f};
          s = mfma16(k0, Q[hp][ns][0], s);
          s = mfma16(k1, Q[hp][ns][1], s);
          #pragma unroll
          for (int r = 0; r < 4; ++r) s[r] = exp2f(s[r] * KSC);
          const int j = ms * 2 + ns;
          pe[hp][j * 2]     = pkbf(s[0], s[1]);
          pe[hp][j * 2 + 1] = pkbf(s[2], s[3]);
          if (hp == 0) {
            #pragma unroll
            for (int r = 0; r < 4; ++r) tt[j * 4 + r] = s[r];
          } else {
            #pragma unroll
            for (int r = 0; r < 4; ++r) tt[j * 4 + r] += s[r];
          }
        }
      }
    }
    #pragma unroll
    for (int j = 0; j < 4; ++j) {
      mySum[j * 2]     = pkbf(tt[j * 4 + 0], tt[j * 4 + 1]);
      mySum[j * 2 + 1] = pkbf(tt[j * 4 + 2], tt[j * 4 + 3]);
    }
  };
  // read all 4 waves' sums -> inv; normalize pe -> pack -> permlane -> pf
  auto build_pf = [&]() {
    float inv[16];
    #pragma unroll
    for (int j = 0; j < 8; ++j) {
      float lo = 0.f, hi = 0.f;
      #pragma unroll
      for (int p = 0; p < 4; ++p) {
        u32 v = sSum[((p << 6) + lane) * 8 + j];
        lo += __builtin_bit_cast(float, v << 16);
        hi += __builtin_bit_cast(float, v & 0xffff0000u);
      }
      inv[j * 2]     = __builtin_amdgcn_rcpf(lo);
      inv[j * 2 + 1] = __builtin_amdgcn_rcpf(hi);
    }
    #pragma unroll
    for (int hp = 0; hp < 2; ++hp)
      #pragma unroll
      for (int ns = 0; ns < 2; ++ns) {
        float p[8];
        #pragma unroll
        for (int jj = 0; jj < 8; ++jj) {
          const int ms = jj >> 2, r = jj & 3;
          const int j8 = (ms * 2 + ns) * 2 + (r >> 1);
          const u32 v = pe[hp][j8];
          const float e = (r & 1) ? __builtin_bit_cast(float, v & 0xffff0000u)
                                  : __builtin_bit_cast(float, v << 16);
          p[jj] = e * inv[j8 * 2 + (r & 1)];
        }
        u32 pa = pkbf(p[0], p[1]), pc = pkbf(p[2], p[3]);
        u32 pb_ = pkbf(p[4], p[5]), pd = pkbf(p[6], p[7]);
        asm("v_permlane32_swap_b32 %0, %1" : "+v"(pa), "+v"(pb_));
        asm("v_permlane16_swap_b32 %0, %1" : "+v"(pa), "+v"(pb_));
        asm("v_permlane32_swap_b32 %0, %1" : "+v"(pc), "+v"(pd));
        asm("v_permlane16_swap_b32 %0, %1" : "+v"(pc), "+v"(pd));
        u32x4 pw; pw.x = pa; pw.y = pc; pw.z = pb_; pw.w = pd;
        pf[hp][ns] = __builtin_bit_cast(sv8, pw);
      }
  };
  auto do_pv = [&]() {
    #pragma unroll
    for (int hp = 0; hp < 2; ++hp)
      #pragma unroll
      for (int dsub = 0; dsub < 4; ++dsub) {
        const int row = (w * 2 + hp) * 64 + dsub * 16 + l15;
        sv8 vf = *(const sv8*)(sV + row * 32 + (g ^ ((l15 >> 1) & 3)) * 8);
        #pragma unroll
        for (int ns = 0; ns < 2; ++ns)
          acc[hp][dsub][ns] = mfma16(pf[hp][ns], vf, acc[hp][dsub][ns]);
      }
  };

  stageK(0); stageV(0);
  __syncthreads();                 // drain stage(0)
  qk_step();                       // tile 0 scores + sums
  for (int t = 0; t < 32; ++t) {
    __syncthreads();               // B2: sums(t) visible, V(t) drained
    if (t < 31) stageK(t + 1);     // in flight under pf-build + PV
    build_pf();
    do_pv();
    __syncthreads();               // B3: K(t+1) drained, sV/sSum free
    if (t < 31) { stageV(t + 1); qk_step(); }  // V in flight under next QK
  }
  // ---- store partials (plain bf16, no atomics) ----
  #pragma unroll
  for (int hp = 0; hp < 2; ++hp)
    #pragma unroll
    for (int dsub = 0; dsub < 4; ++dsub)
      #pragma unroll
      for (int ns = 0; ns < 2; ++ns)
        #pragma unroll
        for (int r = 0; r < 4; ++r)
          pbuf[(size_t)(row0 + ns * 16 + g * 4 + r) * 512
               + (w * 2 + hp) * 64 + dsub * 16 + l15] = f2bf(acc[hp][dsub][ns][r]);
}

// ---------------- combine the two m-half partials -> bf16 ----------------
__global__ __launch_bounds__(256) void cmb(
    const u16* __restrict__ a, const u16* __restrict__ b, u16* __restrict__ o)
{
  const int i = blockIdx.x * 256 + threadIdx.x;  // 524288 total, 8 elems each
  usv8 va = *(const usv8*)(a + (size_t)i * 8);
  usv8 vb = *(const usv8*)(b + (size_t)i * 8);
  usv8 r;
  #pragma unroll
  for (int j = 0; j < 8; ++j) r[j] = f2bf(bf2f(va[j]) + bf2f(vb[j]));
  *(usv8*)(o + (size_t)i * 8) = r;
}

extern "C" void kernel_launch(void* const* d_in, const int* in_sizes, int n_in,
                              void* d_out, int out_size, void* d_ws, size_t ws_size,
                              hipStream_t stream) {
  const float* x      = (const float*)d_in[0];
  const float* ln_g   = (const float*)d_in[1];
  const float* ln_b   = (const float*)d_in[2];
  const float* qkv_w  = (const float*)d_in[3];
  const float* proj_w = (const float*)d_in[4];
  const float* proj_b = (const float*)d_in[5];
  const float* fc1_w  = (const float*)d_in[6];
  const float* fc1_b  = (const float*)d_in[7];
  const float* fc2_w  = (const float*)d_in[8];
  const float* fc2_b  = (const float*)d_in[9];
  char* ws = (char*)d_ws;
  u16*   w_qkv  = (u16*)(ws + 0);         // 1536x512 bf16
  u16*   w_proj = (u16*)(ws + 1572864);   // 512x512
  u16*   w_fc1  = (u16*)(ws + 2097152);   // 2048x512
  u16*   w_fc2  = (u16*)(ws + 4194304);   // 512x2048
  u16*   xn     = (u16*)(ws + 6291456);   // 4096x512 bf16 (LN out; reused as p0)
  u16*   qkvb   = (u16*)(ws + 10485760);  // 4096x1536 bf16
  u16*   vtb    = (u16*)(ws + 23068672);  // [2][8][64][2048] bf16
  u16*   attnb  = (u16*)(ws + 35651584);  // 4096x512 bf16
  float* x1     = (float*)(ws + 39845888);// 4096x512 f32
  u16*   hbuf   = (u16*)(ws + 48234496);  // 4096x2048 bf16 (first 4MB reused as p1)

  u16* pt0 = xn;    // free after qkv GEMM consumes xn
  u16* pt1 = hbuf;  // free until fc1 writes hbuf

  cast_w<<<3072, 256, 0, stream>>>(qkv_w, proj_w, fc1_w, fc2_w,
                                   w_qkv, w_proj, w_fc1, w_fc2);
  ln_kernel<<<1024, 256, 0, stream>>>(x, ln_g, ln_b, xn);
  gemm_kernel<0><<<dim3(32, 12), 256, 0, stream>>>(xn, w_qkv, 512, 1536,
                                                   nullptr, nullptr, qkvb);
  transpose_v<<<dim3(32, 16), 256, 0, stream>>>(qkvb, vtb);
  attn_kernel<<<256, 256, 0, stream>>>(qkvb, vtb, pt0, pt1);
  cmb<<<2048, 256, 0, stream>>>(pt0, pt1, attnb);
  gemm_kernel<1><<<dim3(32, 4), 256, 0, stream>>>(attnb, w_proj, 512, 512,
                                                  proj_b, x, x1);
  ln_kernel<<<1024, 256, 0, stream>>>(x1, ln_g, ln_b, xn);
  gemm_kernel<2><<<dim3(32, 16), 256, 0, stream>>>(xn, w_fc1, 512, 2048,
                                                   fc1_b, nullptr, hbuf);
  gemm_kernel<1><<<dim3(32, 4), 256, 0, stream>>>(hbuf, w_fc2, 2048, 512,
                                                  fc2_b, x1, d_out);
}

// Round 6
// 162.586 us; speedup vs baseline: 2.2518x; 1.1842x over previous
//
#include <hip/hip_runtime.h>

// Transformer layer, MI355X/gfx950.
// B=2, N=2048, C=512, H=8, D=64. Softmax over HEAD axis (faithful to ref).
// Attention v6: 4 head-pair waves share LDS K/V tiles; m-split 4 across
// blocks (512 blocks = 2/CU); conflict-free [j][wave][lane] denominator
// exchange; f32 e-values (no pack round-trip); bf16 partial stores, cmb4.
// GEMM: template BN in {128,64}; BN=64 gives full-CU grids for N=512.

typedef unsigned short u16;
typedef unsigned int u32;
typedef __attribute__((ext_vector_type(4))) float f32x4;
typedef __attribute__((ext_vector_type(4))) u32 u32x4;
typedef __attribute__((ext_vector_type(8))) short sv8;
typedef __attribute__((ext_vector_type(8))) __bf16 bfv8;
typedef __attribute__((ext_vector_type(8))) u16 usv8;
typedef __attribute__((ext_vector_type(4))) u16 usv4;

#define DEV static __device__ __forceinline__

DEV u16 f2bf(float f) {  // RNE fp32 -> bf16
  u32 x = __builtin_bit_cast(u32, f);
  return (u16)((x + 0x7fffu + ((x >> 16) & 1u)) >> 16);
}

DEV float bf2f(u16 v) { return __builtin_bit_cast(float, (u32)v << 16); }

DEV f32x4 mfma16(sv8 a, sv8 b, f32x4 c) {
  return __builtin_amdgcn_mfma_f32_16x16x32_bf16(
      __builtin_bit_cast(bfv8, a), __builtin_bit_cast(bfv8, b), c, 0, 0, 0);
}

DEV void gload_lds16(const void* g, void* l) {
  __builtin_amdgcn_global_load_lds(
      (const __attribute__((address_space(1))) u32*)g,
      (__attribute__((address_space(3))) u32*)l, 16, 0, 0);
}

DEV u32 pkbf(float a, float b) {
  u32 r;
  asm("v_cvt_pk_bf16_f32 %0, %1, %2" : "=v"(r) : "v"(a), "v"(b));
  return r;
}

// ---------------- weight cast: 4 fp32 weight mats -> bf16 ----------------
__global__ __launch_bounds__(256) void cast_w(
    const float* __restrict__ s0, const float* __restrict__ s1,
    const float* __restrict__ s2, const float* __restrict__ s3,
    u16* __restrict__ d0, u16* __restrict__ d1,
    u16* __restrict__ d2, u16* __restrict__ d3)
{
  int i = blockIdx.x * 256 + threadIdx.x;  // vec4 index, 786432 total
  const float* s; u16* d; int off;
  if (i < 196608)      { s = s0; d = d0; off = i; }
  else if (i < 262144) { s = s1; d = d1; off = i - 196608; }
  else if (i < 524288) { s = s2; d = d2; off = i - 262144; }
  else                 { s = s3; d = d3; off = i - 524288; }
  float4 v = ((const float4*)s)[off];
  usv4 r; r.x = f2bf(v.x); r.y = f2bf(v.y); r.z = f2bf(v.z); r.w = f2bf(v.w);
  *(usv4*)(d + (size_t)off * 4) = r;
}

// ---------------- layernorm (C=512) fp32 in -> bf16 out ----------------
__global__ __launch_bounds__(256) void ln_kernel(
    const float* __restrict__ x, const float* __restrict__ g,
    const float* __restrict__ bb, u16* __restrict__ out)
{
  const int row = (blockIdx.x << 2) + (threadIdx.x >> 6);
  const int lane = threadIdx.x & 63;
  const float4* xr = (const float4*)(x + ((size_t)row << 9));
  float4 a = xr[lane * 2], c = xr[lane * 2 + 1];
  float s  = a.x + a.y + a.z + a.w + c.x + c.y + c.z + c.w;
  float ss = a.x*a.x + a.y*a.y + a.z*a.z + a.w*a.w
           + c.x*c.x + c.y*c.y + c.z*c.z + c.w*c.w;
  #pragma unroll
  for (int off = 32; off; off >>= 1) { s += __shfl_xor(s, off); ss += __shfl_xor(ss, off); }
  const float mu = s * (1.0f / 512.0f);
  const float rstd = rsqrtf(ss * (1.0f / 512.0f) - mu * mu + 1e-6f);
  const float4* g4 = (const float4*)g;
  const float4* b4 = (const float4*)bb;
  float4 g0 = g4[lane * 2], g1 = g4[lane * 2 + 1];
  float4 b0 = b4[lane * 2], b1 = b4[lane * 2 + 1];
  usv8 rr;
  rr[0] = f2bf((a.x - mu) * rstd * g0.x + b0.x);
  rr[1] = f2bf((a.y - mu) * rstd * g0.y + b0.y);
  rr[2] = f2bf((a.z - mu) * rstd * g0.z + b0.z);
  rr[3] = f2bf((a.w - mu) * rstd * g0.w + b0.w);
  rr[4] = f2bf((c.x - mu) * rstd * g1.x + b1.x);
  rr[5] = f2bf((c.y - mu) * rstd * g1.y + b1.y);
  rr[6] = f2bf((c.z - mu) * rstd * g1.z + b1.z);
  rr[7] = f2bf((c.w - mu) * rstd * g1.w + b1.w);
  *(usv8*)(out + ((size_t)row << 9) + (lane << 3)) = rr;
}

// ---------------- GEMM: out[m][o] = sum_c A[m][c] * W[o][c] (+epilogue) ----
// Tile 128 x BN, 4 waves. EPI 0: bf16 store. EPI 1: f32 acc+bias+res.
// EPI 2: bf16 gelu(acc+bias).
template<int EPI, int BN>
__global__ __launch_bounds__(256, (BN == 64) ? 3 : 2) void gemm_kernel(
    const u16* __restrict__ A, const u16* __restrict__ W,
    int K, int Nn, const float* __restrict__ bias,
    const float* __restrict__ res, void* __restrict__ outp)
{
  __shared__ u16 sA[128 * 64];
  __shared__ u16 sB[BN * 64];
  constexpr int MI = (BN == 128) ? 4 : 2;     // 16-row m-frags per wave
  const int m0 = blockIdx.x << 7, n0 = blockIdx.y * BN;
  const int lane = threadIdx.x & 63, wave = threadIdx.x >> 6;
  const int wm = (BN == 128) ? (wave >> 1) : wave;
  const int wn = (BN == 128) ? (wave & 1) : 0;
  const int srow = lane >> 3, scol = (lane & 7) << 3;
  const int l15 = lane & 15, g = lane >> 4;
  f32x4 acc[MI][4] = {};
  for (int kt = 0; kt < K; kt += 64) {
    #pragma unroll
    for (int i = 0; i < 4; ++i) {
      const int c = (wave << 2) + i;
      gload_lds16(A + (size_t)(m0 + (c << 3) + srow) * K + kt + scol, sA + (c << 9));
    }
    if (BN == 128) {
      #pragma unroll
      for (int i = 0; i < 4; ++i) {
        const int c = (wave << 2) + i;
        gload_lds16(W + (size_t)(n0 + (c << 3) + srow) * K + kt + scol, sB + (c << 9));
      }
    } else {
      #pragma unroll
      for (int i = 0; i < 2; ++i) {
        const int c = (wave << 1) + i;
        gload_lds16(W + (size_t)(n0 + (c << 3) + srow) * K + kt + scol, sB + (c << 9));
      }
    }
    __syncthreads();
    #pragma unroll
    for (int kk = 0; kk < 2; ++kk) {
      sv8 af[MI], bfr[4];
      #pragma unroll
      for (int mi = 0; mi < MI; ++mi)
        af[mi] = *(const sv8*)(sA + (wm * (16 * MI) + mi * 16 + l15) * 64 + kk * 32 + (g << 3));
      #pragma unroll
      for (int ni = 0; ni < 4; ++ni)
        bfr[ni] = *(const sv8*)(sB + (wn * 64 + ni * 16 + l15) * 64 + kk * 32 + (g << 3));
      #pragma unroll
      for (int mi = 0; mi < MI; ++mi)
        #pragma unroll
        for (int ni = 0; ni < 4; ++ni)
          acc[mi][ni] = mfma16(af[mi], bfr[ni], acc[mi][ni]);
    }
    __syncthreads();
  }
  float bias_v[4];
  if (EPI != 0) {
    #pragma unroll
    for (int ni = 0; ni < 4; ++ni)
      bias_v[ni] = bias[n0 + wn * 64 + ni * 16 + l15];
  }
  #pragma unroll
  for (int mi = 0; mi < MI; ++mi) {
    #pragma unroll
    for (int ni = 0; ni < 4; ++ni) {
      const int gcol = n0 + wn * 64 + ni * 16 + l15;
      #pragma unroll
      for (int r = 0; r < 4; ++r) {
        const int grow = m0 + wm * (16 * MI) + mi * 16 + (g << 2) + r;
        float v = acc[mi][ni][r];
        if (EPI == 0) {
          ((u16*)outp)[(size_t)grow * Nn + gcol] = f2bf(v);
        } else if (EPI == 1) {
          ((float*)outp)[(size_t)grow * Nn + gcol] =
              v + bias_v[ni] + res[(size_t)grow * Nn + gcol];
        } else {
          float t = v + bias_v[ni];
          float gl = 0.5f * t * (1.0f + erff(t * 0.70710678118654752f));
          ((u16*)outp)[(size_t)grow * Nn + gcol] = f2bf(gl);
        }
      }
    }
  }
}

// ---------------- V transpose: qkv V-part -> vt[b][h][d][n] ----------------
__global__ __launch_bounds__(256) void transpose_v(
    const u16* __restrict__ qkvb, u16* __restrict__ vt)
{
  __shared__ u16 tile[64][72];
  const int bh = blockIdx.y, n0 = blockIdx.x << 6;
  const int b = bh >> 3, h = bh & 7;
  const int t = threadIdx.x;
  const int row = t >> 2, d0 = (t & 3) << 4;
  const u16* src = qkvb + (size_t)(b * 2048 + n0 + row) * 1536 + 1024 + h * 64 + d0;
  *(uint4*)&tile[row][d0]     = *(const uint4*)src;
  *(uint4*)&tile[row][d0 + 8] = *(const uint4*)(src + 8);
  __syncthreads();
  const int dr = t >> 2, nn0 = (t & 3) << 4;
  u16* dst = vt + (size_t)(bh * 64 + dr) * 2048 + n0 + nn0;
  usv8 v0, v1;
  #pragma unroll
  for (int j = 0; j < 8; ++j) v0[j] = tile[nn0 + j][dr];
  #pragma unroll
  for (int j = 0; j < 8; ++j) v1[j] = tile[nn0 + 8 + j][dr];
  *(usv8*)dst = v0;
  *(usv8*)(dst + 8) = v1;
}

// ---------------- fused attention v6 (softmax over heads) ----------------
// 512 blocks x 256 thr (4 waves), 2 blocks/CU. Block = 32 n-rows x 512-m
// quarter; wave w owns heads {2w,2w+1}. K/V tiles shared via LDS; denom
// exchange in [j][wave][lane] layout (conflict-free).
__global__ __launch_bounds__(256, 2) void attn_kernel(
    const u16* __restrict__ qkvb, const u16* __restrict__ vt,
    u16* __restrict__ p0, u16* __restrict__ p1,
    u16* __restrict__ p2, u16* __restrict__ p3)
{
  __shared__ u16 sK[8 * 32 * 64];   // 32KB [h][m32][slot8], slot^=(m&7)
  __shared__ u16 sV[512 * 32];      // 32KB [h*64+d][slot4], slot^=((row>>1)&3)
  __shared__ u32 sSum[8 * 256];     // 8KB  [j][wave][lane] bf16-pair sums
  const int tid = threadIdx.x;
  const int lane = tid & 63, w = tid >> 6;
  const int l15 = lane & 15, g = lane >> 4;

  const int swz = ((blockIdx.x & 7) << 6) + (blockIdx.x >> 3);  // XCD swizzle
  const int msplit = swz >> 7;          // 0..3
  const int strip = swz & 127;
  const int row0 = strip << 5;          // global row 0..4095
  const int b = row0 >> 11;
  const int m0 = msplit << 9;           // m-offset within batch; 16 tiles of 32
  u16* pbuf = (msplit < 2) ? (msplit ? p1 : p0) : ((msplit == 2) ? p2 : p3);
  const float KSC = 0.125f * 1.4426950408889634f;  // scale * log2(e)

  // ---- Q hoist ----
  sv8 Q[2][2][2];
  #pragma unroll
  for (int hp = 0; hp < 2; ++hp)
    #pragma unroll
    for (int ns = 0; ns < 2; ++ns) {
      const u16* qp = qkvb + (size_t)(row0 + ns * 16 + l15) * 1536
                    + (w * 2 + hp) * 64 + g * 8;
      Q[hp][ns][0] = *(const sv8*)qp;
      Q[hp][ns][1] = *(const sv8*)(qp + 32);
    }

  // staging bases (pre-swizzled global sources, linear LDS dst)
  const u16* pK = qkvb + (size_t)(b * 2048 + m0 + (lane >> 3)) * 1536 + 512
                + ((lane & 7) ^ (lane >> 3)) * 8 + w * 128;
  const u16* pV = vt + (size_t)(b * 512 + w * 128 + (lane >> 2)) * 2048 + m0
                + ((lane & 3) ^ ((lane >> 3) & 3)) * 8;

  float pe_f[2][2][2][4];   // [hp][ms][ns][r] e-values
  sv8 pf[2][2];             // P^T A-frags [hp][ns]
  f32x4 acc[2][4][2] = {};

  auto stageK = [&](int t) {
    const u16* base = pK + (size_t)t * (32 * 1536);
    #pragma unroll
    for (int i = 0; i < 8; ++i)
      gload_lds16(base + (i >> 2) * 64 + (i & 3) * 12288,
                  sK + ((w << 3) + i) * 512);
  };
  auto stageV = [&](int t) {
    const u16* base = pV + t * 32;
    #pragma unroll
    for (int i = 0; i < 8; ++i)
      gload_lds16(base + (size_t)i * 32768, sV + ((w << 3) + i) * 512);
  };
  // QK^T for own 2 heads -> exp -> pe_f + bf16-pair partial sums -> LDS
  auto qk_step = [&]() {
    #pragma unroll
    for (int hp = 0; hp < 2; ++hp)
      #pragma unroll
      for (int ms = 0; ms < 2; ++ms) {
        const int row = ((w * 2 + hp) * 32 + ms * 16 + l15) * 64;
        const int x7 = l15 & 7;
        sv8 k0 = *(const sv8*)(sK + row + (g ^ x7) * 8);
        sv8 k1 = *(const sv8*)(sK + row + ((4 + g) ^ x7) * 8);
        #pragma unroll
        for (int ns = 0; ns < 2; ++ns) {
          f32x4 s = {0.f, 0.f, 0.f, 0.f};
          s = mfma16(k0, Q[hp][ns][0], s);
          s = mfma16(k1, Q[hp][ns][1], s);
          #pragma unroll
          for (int r = 0; r < 4; ++r) pe_f[hp][ms][ns][r] = exp2f(s[r] * KSC);
        }
      }
    #pragma unroll
    for (int ms = 0; ms < 2; ++ms)
      #pragma unroll
      for (int ns = 0; ns < 2; ++ns) {
        const int mn = ms * 2 + ns;
        sSum[(mn * 2) * 256 + (w << 6) + lane] =
            pkbf(pe_f[0][ms][ns][0] + pe_f[1][ms][ns][0],
                 pe_f[0][ms][ns][1] + pe_f[1][ms][ns][1]);
        sSum[(mn * 2 + 1) * 256 + (w << 6) + lane] =
            pkbf(pe_f[0][ms][ns][2] + pe_f[1][ms][ns][2],
                 pe_f[0][ms][ns][3] + pe_f[1][ms][ns][3]);
      }
  };
  // read all 4 waves' sums -> inv; normalize -> pack -> permlane -> pf
  auto build_pf = [&]() {
    float inv[2][2][4];
    #pragma unroll
    for (int ms = 0; ms < 2; ++ms)
      #pragma unroll
      for (int ns = 0; ns < 2; ++ns)
        #pragma unroll
        for (int rh = 0; rh < 2; ++rh) {
          const int j8 = (ms * 2 + ns) * 2 + rh;
          float lo = 0.f, hi = 0.f;
          #pragma unroll
          for (int p = 0; p < 4; ++p) {
            u32 v = sSum[j8 * 256 + (p << 6) + lane];
            lo += __builtin_bit_cast(float, v << 16);
            hi += __builtin_bit_cast(float, v & 0xffff0000u);
          }
          inv[ms][ns][rh * 2]     = __builtin_amdgcn_rcpf(lo);
          inv[ms][ns][rh * 2 + 1] = __builtin_amdgcn_rcpf(hi);
        }
    #pragma unroll
    for (int hp = 0; hp < 2; ++hp)
      #pragma unroll
      for (int ns = 0; ns < 2; ++ns) {
        float p[8];
        #pragma unroll
        for (int ms = 0; ms < 2; ++ms)
          #pragma unroll
          for (int r = 0; r < 4; ++r)
            p[ms * 4 + r] = pe_f[hp][ms][ns][r] * inv[ms][ns][r];
        u32 pa = pkbf(p[0], p[1]), pc = pkbf(p[2], p[3]);
        u32 pb_ = pkbf(p[4], p[5]), pd = pkbf(p[6], p[7]);
        asm("v_permlane32_swap_b32 %0, %1" : "+v"(pa), "+v"(pb_));
        asm("v_permlane16_swap_b32 %0, %1" : "+v"(pa), "+v"(pb_));
        asm("v_permlane32_swap_b32 %0, %1" : "+v"(pc), "+v"(pd));
        asm("v_permlane16_swap_b32 %0, %1" : "+v"(pc), "+v"(pd));
        u32x4 pw; pw.x = pa; pw.y = pc; pw.z = pb_; pw.w = pd;
        pf[hp][ns] = __builtin_bit_cast(sv8, pw);
      }
  };
  auto do_pv = [&]() {
    #pragma unroll
    for (int hp = 0; hp < 2; ++hp)
      #pragma unroll
      for (int dsub = 0; dsub < 4; ++dsub) {
        const int row = (w * 2 + hp) * 64 + dsub * 16 + l15;
        sv8 vf = *(const sv8*)(sV + row * 32 + (g ^ ((l15 >> 1) & 3)) * 8);
        #pragma unroll
        for (int ns = 0; ns < 2; ++ns)
          acc[hp][dsub][ns] = mfma16(pf[hp][ns], vf, acc[hp][dsub][ns]);
      }
  };

  stageK(0); stageV(0);
  __syncthreads();                 // drain stage(0)
  qk_step();                       // tile 0 scores + sums
  for (int t = 0; t < 16; ++t) {
    __syncthreads();               // B2: sums(t) visible, V(t) drained
    if (t < 15) stageK(t + 1);     // in flight under pf-build + PV
    build_pf();
    do_pv();
    __syncthreads();               // B3: K(t+1) drained, sV/sSum free
    if (t < 15) { stageV(t + 1); qk_step(); }  // V in flight under next QK
  }
  // ---- store partials (plain bf16, no atomics) ----
  #pragma unroll
  for (int hp = 0; hp < 2; ++hp)
    #pragma unroll
    for (int dsub = 0; dsub < 4; ++dsub)
      #pragma unroll
      for (int ns = 0; ns < 2; ++ns)
        #pragma unroll
        for (int r = 0; r < 4; ++r)
          pbuf[(size_t)(row0 + ns * 16 + g * 4 + r) * 512
               + (w * 2 + hp) * 64 + dsub * 16 + l15] = f2bf(acc[hp][dsub][ns][r]);
}

// ---------------- combine the four m-quarter partials -> bf16 ----------------
__global__ __launch_bounds__(256) void cmb4(
    const u16* __restrict__ a, const u16* __restrict__ b,
    const u16* __restrict__ c, const u16* __restrict__ d,
    u16* __restrict__ o)
{
  const int i = blockIdx.x * 256 + threadIdx.x;  // 262144 total, 8 elems each
  usv8 va = *(const usv8*)(a + (size_t)i * 8);
  usv8 vb = *(const usv8*)(b + (size_t)i * 8);
  usv8 vc = *(const usv8*)(c + (size_t)i * 8);
  usv8 vd = *(const usv8*)(d + (size_t)i * 8);
  usv8 r;
  #pragma unroll
  for (int j = 0; j < 8; ++j)
    r[j] = f2bf((bf2f(va[j]) + bf2f(vb[j])) + (bf2f(vc[j]) + bf2f(vd[j])));
  *(usv8*)(o + (size_t)i * 8) = r;
}

extern "C" void kernel_launch(void* const* d_in, const int* in_sizes, int n_in,
                              void* d_out, int out_size, void* d_ws, size_t ws_size,
                              hipStream_t stream) {
  const float* x      = (const float*)d_in[0];
  const float* ln_g   = (const float*)d_in[1];
  const float* ln_b   = (const float*)d_in[2];
  const float* qkv_w  = (const float*)d_in[3];
  const float* proj_w = (const float*)d_in[4];
  const float* proj_b = (const float*)d_in[5];
  const float* fc1_w  = (const float*)d_in[6];
  const float* fc1_b  = (const float*)d_in[7];
  const float* fc2_w  = (const float*)d_in[8];
  const float* fc2_b  = (const float*)d_in[9];
  char* ws = (char*)d_ws;
  u16*   w_qkv  = (u16*)(ws + 0);         // 1536x512 bf16
  u16*   w_proj = (u16*)(ws + 1572864);   // 512x512
  u16*   w_fc1  = (u16*)(ws + 2097152);   // 2048x512
  u16*   w_fc2  = (u16*)(ws + 4194304);   // 512x2048
  u16*   xn     = (u16*)(ws + 6291456);   // 4096x512 bf16 (LN out; reused as pt0)
  u16*   qkvb   = (u16*)(ws + 10485760);  // 4096x1536 bf16
  u16*   vtb    = (u16*)(ws + 23068672);  // [2][8][64][2048] bf16
  u16*   attnb  = (u16*)(ws + 35651584);  // 4096x512 bf16
  float* x1     = (float*)(ws + 39845888);// 4096x512 f32
  u16*   hbuf   = (u16*)(ws + 48234496);  // 4096x2048 bf16 (pt1..pt3 pre-fc1)

  u16* pt0 = xn;                 // free after qkv GEMM consumes xn
  u16* pt1 = hbuf;               // hbuf free until fc1
  u16* pt2 = hbuf + 2097152;
  u16* pt3 = hbuf + 4194304;

  cast_w<<<3072, 256, 0, stream>>>(qkv_w, proj_w, fc1_w, fc2_w,
                                   w_qkv, w_proj, w_fc1, w_fc2);
  ln_kernel<<<1024, 256, 0, stream>>>(x, ln_g, ln_b, xn);
  gemm_kernel<0, 64><<<dim3(32, 24), 256, 0, stream>>>(xn, w_qkv, 512, 1536,
                                                       nullptr, nullptr, qkvb);
  transpose_v<<<dim3(32, 16), 256, 0, stream>>>(qkvb, vtb);
  attn_kernel<<<512, 256, 0, stream>>>(qkvb, vtb, pt0, pt1, pt2, pt3);
  cmb4<<<1024, 256, 0, stream>>>(pt0, pt1, pt2, pt3, attnb);
  gemm_kernel<1, 64><<<dim3(32, 8), 256, 0, stream>>>(attnb, w_proj, 512, 512,
                                                      proj_b, x, x1);
  ln_kernel<<<1024, 256, 0, stream>>>(x1, ln_g, ln_b, xn);
  gemm_kernel<2, 128><<<dim3(32, 16), 256, 0, stream>>>(xn, w_fc1, 512, 2048,
                                                        fc1_b, nullptr, hbuf);
  gemm_kernel<1, 64><<<dim3(32, 8), 256, 0, stream>>>(hbuf, w_fc2, 2048, 512,
                                                      fc2_b, x1, d_out);
}